// Round 13
// baseline (186.777 us; speedup 1.0000x reference)
//
#include <hip/hip_runtime.h>
#include <math.h>

#define BB 4
#define TT 600
#define FQ 481
#define NW 5
#define TOTAL (BB * TT * FQ)

// libgcc __divsc3 specialized to (1 + 0i) / (c + di): pure float Smith,
// den = c*r + d (or c + d*r), DIRECT divisions for both components,
// branch predicate |c| < |d| (ties -> else). No FMA (libgcc is baseline).
__device__ __forceinline__ void divsc3_recip(float c, float d, float& zr, float& zi) {
    if (fabsf(c) < fabsf(d)) {
        float ratio = c / d;
        float m = c * ratio;
        float den = m + d;
        zr = ratio / den;
        zi = -1.0f / den;
    } else {
        float ratio = d / c;
        float m = d * ratio;
        float den = c + m;
        zr = 1.0f / den;
        zi = -ratio / den;
    }
}

__global__ __launch_bounds__(64) void mfwf_kernel(
    const float* __restrict__ spec,   // (B,1,T,FQ,2)
    const float* __restrict__ ifc,    // (B,T,FQ,10)
    const float* __restrict__ iRxx,   // (B,T,FQ,50)
    float* __restrict__ out)          // (B,1,T,FQ,2)
{
    #pragma clang fp contract(off)
    // 64 systems x 50 floats, rows padded to 51 words (13,056 B):
    // gcd(51,32)=1 -> strided reads AND near-sequential writes are
    // <=2 lanes/bank (free, m136). ~12 blocks/CU keep phases pipelined.
    __shared__ float sR[64 * 51];

    int tid = threadIdx.x;
    int base = blockIdx.x * 64;
    int idx = base + tid;

    // ---- coalesced global -> LDS transpose staging of iRxx ----
    {
        size_t cbase = (size_t)base * 50;
        size_t limR = (size_t)TOTAL * 50;
        #pragma unroll
        for (int w = 0; w < 50; w++) {
            int flat = w * 64 + tid;
            size_t g = cbase + (size_t)flat;
            float v = 0.0f;
            if (g < limR) v = iRxx[g];
            int s = flat / 50;
            int e = flat - s * 50;
            sR[s * 51 + e] = v;
        }
    }
    __syncthreads();   // 1-wave block: compiles to a waitcnt, no barrier cost

    if (idx >= TOTAL) return;

    int f  = idx % FQ;
    int bt = idx / FQ;
    int t  = bt % TT;
    int b  = bt / TT;

    // ---- read A row from LDS (stride-51 rows: conflict-free) ----
    const float* rp = &sR[tid * 51];
    float Ar[NW][NW], Ai[NW][NW];
    #pragma unroll
    for (int i = 0; i < NW; i++) {
        #pragma unroll
        for (int j = 0; j < NW; j++) {
            Ar[i][j] = rp[(i * NW + j) * 2];
            Ai[i][j] = rp[(i * NW + j) * 2 + 1];
        }
    }

    // ---- Hermitianize + diagonal load (fp32, two roundings for dload) ----
    float tr0 = (((Ar[0][0] + Ar[1][1]) + Ar[2][2]) + Ar[3][3]) + Ar[4][4];
    float dml = tr0 * 1e-7f;
    float dload = dml + 1e-8f;
    #pragma unroll
    for (int i = 0; i < NW; i++) {
        Ai[i][i] = 0.0f;
        #pragma unroll
        for (int j = i + 1; j < NW; j++) {
            Ar[i][j] = Ar[j][i];
            Ai[i][j] = -Ai[j][i];
        }
    }
    #pragma unroll
    for (int i = 0; i < NW; i++) {
        Ar[i][i] = Ar[i][i] + dload;
    }

    // ---- rhs (direct, 40 B/thread) ----
    const float2* gp = (const float2*)(ifc + (size_t)idx * 10);
    float yr[NW], yi[NW];
    #pragma unroll
    for (int n = 0; n < NW; n++) {
        float2 v = gp[n];
        yr[n] = v.x;
        yi[n] = v.y;
    }

    // ==== netlib cgetf2 (gfortran) + OpenBLAS FMA-contracted kernels ====
    #pragma unroll
    for (int k = 0; k < NW; k++) {
        // icamax: first max of CABS1 = |re|+|im| (float), strict >
        int bi = k;
        float bm = fabsf(Ar[k][k]) + fabsf(Ai[k][k]);
        #pragma unroll
        for (int i = k + 1; i < NW; i++) {
            float m = fabsf(Ar[i][k]) + fabsf(Ai[i][k]);
            if (m > bm) { bm = m; bi = i; }
        }
        // full-row swap k <-> bi + rhs (laswp-equivalent interleave)
        #pragma unroll
        for (int i = k + 1; i < NW; i++) {
            bool sw = (bi == i);
            #pragma unroll
            for (int j = 0; j < NW; j++) {
                float a = Ar[k][j], c = Ar[i][j];
                Ar[k][j] = sw ? c : a;  Ar[i][j] = sw ? a : c;
                a = Ai[k][j]; c = Ai[i][j];
                Ai[k][j] = sw ? c : a;  Ai[i][j] = sw ? a : c;
            }
            float a = yr[k], c = yr[i];
            yr[k] = sw ? c : a;  yr[i] = sw ? a : c;
            a = yi[k]; c = yi[i];
            yi[k] = sw ? c : a;  yi[i] = sw ? a : c;
        }
        // CONE / A(k,k) via exact __divsc3 (direct divisions)
        float ivr, ivi;
        divsc3_recip(Ar[k][k], Ai[k][k], ivr, ivi);
        // CSCAL tail (arch-compiled, FMA-contracted)
        #pragma unroll
        for (int i = k + 1; i < NW; i++) {
            float xr_ = Ar[i][k], xi_ = Ai[i][k];
            float Lr = fmaf(ivr, xr_, -(ivi * xi_));
            float Li = fmaf(ivr, xi_,  (ivi * xr_));
            Ar[i][k] = Lr;
            Ai[i][k] = Li;
        }
        // CGERU (FMA-contracted), alpha = -1: temp = -U[k][j] exact
        #pragma unroll
        for (int j = k + 1; j < NW; j++) {
            float tr_ = -Ar[k][j], ti_ = -Ai[k][j];
            #pragma unroll
            for (int i = k + 1; i < NW; i++) {
                Ar[i][j] = Ar[i][j] + fmaf(tr_, Ar[i][k], -(ti_ * Ai[i][k]));
                Ai[i][j] = Ai[i][j] + fmaf(tr_, Ai[i][k],  (ti_ * Ar[i][k]));
            }
        }
        // forward solve on rhs (laswp + unit-L ctrsm, FMA shapes)
        #pragma unroll
        for (int i = k + 1; i < NW; i++) {
            yr[i] = yr[i] - fmaf(Ar[i][k], yr[k], -(Ai[i][k] * yi[k]));
            yi[i] = yi[i] - fmaf(Ar[i][k], yi[k],  (Ai[i][k] * yr[k]));
        }
    }

    // ==== backward solve (upper non-unit ctrsm): pre-inverted diagonal
    //      (c+d*r, FMA denom), FMA-contracted multiply/axpy ====
    float xr[NW], xi[NW];
    #pragma unroll
    for (int k = NW - 1; k >= 0; k--) {
        float ur = Ar[k][k], ui = Ai[k][k];
        float ivr, ivi;
        if (fabsf(ur) >= fabsf(ui)) {
            float ratio = ui / ur;
            float s = fmaf(ui, ratio, ur);
            float den = 1.0f / s;
            ivr = den;
            ivi = -(ratio * den);
        } else {
            float ratio = ur / ui;
            float s = fmaf(ur, ratio, ui);
            float den = 1.0f / s;
            ivr = ratio * den;
            ivi = -den;
        }
        float xkr = fmaf(ivr, yr[k], -(ivi * yi[k]));
        float xki = fmaf(ivr, yi[k],  (ivi * yr[k]));
        xr[k] = xkr;
        xi[k] = xki;
        #pragma unroll
        for (int i = 0; i < k; i++) {
            yr[i] = yr[i] - fmaf(xkr, Ar[i][k], -(xki * Ai[i][k]));
            yi[i] = yi[i] - fmaf(xkr, Ai[i][k],  (xki * Ar[i][k]));
        }
    }

    // ==== windowed spec dot, plain fp32, ascending n ====
    const float2* sp = (const float2*)spec;
    size_t bbase = (size_t)b * TT;
    float o_r = 0.0f, o_i = 0.0f;
    #pragma unroll
    for (int n = 0; n < NW; n++) {
        int tt2 = t + n - 3;
        if (tt2 >= 0 && tt2 < TT) {
            float2 v = sp[(bbase + (size_t)tt2) * FQ + f];
            float p1 = v.x * xr[n];
            float p2 = v.y * xi[n];
            o_r = o_r + (p1 - p2);
            float p3 = v.x * xi[n];
            float p4 = v.y * xr[n];
            o_i = o_i + (p3 + p4);
        }
    }

    float2 o;
    o.x = o_r;
    o.y = o_i;
    ((float2*)out)[idx] = o;
}

extern "C" void kernel_launch(void* const* d_in, const int* in_sizes, int n_in,
                              void* d_out, int out_size, void* d_ws, size_t ws_size,
                              hipStream_t stream) {
    const float* spec = (const float*)d_in[0];
    const float* ifc  = (const float*)d_in[1];
    const float* iRxx = (const float*)d_in[2];
    float* out = (float*)d_out;

    int blocks = (TOTAL + 63) / 64;
    mfwf_kernel<<<blocks, 64, 0, stream>>>(spec, ifc, iRxx, out);
}

// Round 14
// 55.879 us; speedup vs baseline: 3.3425x; 3.3425x over previous
//
#include <hip/hip_runtime.h>
#include <math.h>

#define BB 4
#define TT 600
#define FQ 481
#define NW 5
#define TOTAL (BB * TT * FQ)

// libgcc __divsc3 specialized to (1 + 0i) / (c + di): pure float Smith,
// den = c*r + d (or c + d*r), DIRECT divisions for both components,
// branch predicate |c| < |d| (ties -> else). No FMA (libgcc is baseline).
__device__ __forceinline__ void divsc3_recip(float c, float d, float& zr, float& zi) {
    if (fabsf(c) < fabsf(d)) {
        float ratio = c / d;
        float m = c * ratio;
        float den = m + d;
        zr = ratio / den;
        zi = -1.0f / den;
    } else {
        float ratio = d / c;
        float m = d * ratio;
        float den = c + m;
        zr = 1.0f / den;
        zi = -ratio / den;
    }
}

__global__ __launch_bounds__(256) void mfwf_kernel(
    const float* __restrict__ spec,   // (B,1,T,FQ,2)
    const float* __restrict__ ifc,    // (B,T,FQ,10)
    const float* __restrict__ iRxx,   // (B,T,FQ,50)
    float* __restrict__ out)          // (B,1,T,FQ,2)
{
    #pragma clang fp contract(off)
    int idx = blockIdx.x * 256 + threadIdx.x;
    if (idx >= TOTAL) return;

    int f  = idx % FQ;
    int bt = idx / FQ;
    int t  = bt % TT;
    int b  = bt / TT;

    // ---- load iRxx (50 floats contiguous per thread) ----
    const float2* rp = (const float2*)(iRxx + (size_t)idx * 50);
    float Ar[NW][NW], Ai[NW][NW];
    #pragma unroll
    for (int i = 0; i < NW; i++) {
        #pragma unroll
        for (int j = 0; j < NW; j++) {
            float2 v = rp[i * NW + j];
            Ar[i][j] = v.x;
            Ai[i][j] = v.y;
        }
    }

    // ---- Hermitianize + diagonal load (fp32, two roundings for dload) ----
    float tr0 = (((Ar[0][0] + Ar[1][1]) + Ar[2][2]) + Ar[3][3]) + Ar[4][4];
    float dml = tr0 * 1e-7f;
    float dload = dml + 1e-8f;
    #pragma unroll
    for (int i = 0; i < NW; i++) {
        Ai[i][i] = 0.0f;
        #pragma unroll
        for (int j = i + 1; j < NW; j++) {
            Ar[i][j] = Ar[j][i];
            Ai[i][j] = -Ai[j][i];
        }
    }
    #pragma unroll
    for (int i = 0; i < NW; i++) {
        Ar[i][i] = Ar[i][i] + dload;
    }

    // ---- rhs ----
    const float2* gp = (const float2*)(ifc + (size_t)idx * 10);
    float yr[NW], yi[NW];
    #pragma unroll
    for (int n = 0; n < NW; n++) {
        float2 v = gp[n];
        yr[n] = v.x;
        yi[n] = v.y;
    }

    // ==== netlib cgetf2 (gfortran) + OpenBLAS FMA-contracted kernels ====
    #pragma unroll
    for (int k = 0; k < NW; k++) {
        // icamax: first max of CABS1 = |re|+|im| (float), strict >
        int bi = k;
        float bm = fabsf(Ar[k][k]) + fabsf(Ai[k][k]);
        #pragma unroll
        for (int i = k + 1; i < NW; i++) {
            float m = fabsf(Ar[i][k]) + fabsf(Ai[i][k]);
            if (m > bm) { bm = m; bi = i; }
        }
        // swap rows k <-> bi on columns >= k only (cols < k are dead:
        // factorization reads col >= k; fwd-solve consumed col < k already;
        // backsolve reads rows < k which these swaps never touch) + rhs.
        // Bit-identical to the full-row (laswp) variant.
        #pragma unroll
        for (int i = k + 1; i < NW; i++) {
            bool sw = (bi == i);
            #pragma unroll
            for (int j = k; j < NW; j++) {
                float a = Ar[k][j], c = Ar[i][j];
                Ar[k][j] = sw ? c : a;  Ar[i][j] = sw ? a : c;
                a = Ai[k][j]; c = Ai[i][j];
                Ai[k][j] = sw ? c : a;  Ai[i][j] = sw ? a : c;
            }
            float a = yr[k], c = yr[i];
            yr[k] = sw ? c : a;  yr[i] = sw ? a : c;
            a = yi[k]; c = yi[i];
            yi[k] = sw ? c : a;  yi[i] = sw ? a : c;
        }
        // CONE / A(k,k) via exact __divsc3 (direct divisions)
        float ivr, ivi;
        divsc3_recip(Ar[k][k], Ai[k][k], ivr, ivi);
        // CSCAL tail (arch-compiled, FMA-contracted)
        #pragma unroll
        for (int i = k + 1; i < NW; i++) {
            float xr_ = Ar[i][k], xi_ = Ai[i][k];
            float Lr = fmaf(ivr, xr_, -(ivi * xi_));
            float Li = fmaf(ivr, xi_,  (ivi * xr_));
            Ar[i][k] = Lr;
            Ai[i][k] = Li;
        }
        // CGERU (FMA-contracted), alpha = -1: temp = -U[k][j] exact
        #pragma unroll
        for (int j = k + 1; j < NW; j++) {
            float tr_ = -Ar[k][j], ti_ = -Ai[k][j];
            #pragma unroll
            for (int i = k + 1; i < NW; i++) {
                Ar[i][j] = Ar[i][j] + fmaf(tr_, Ar[i][k], -(ti_ * Ai[i][k]));
                Ai[i][j] = Ai[i][j] + fmaf(tr_, Ai[i][k],  (ti_ * Ar[i][k]));
            }
        }
        // forward solve on rhs (laswp + unit-L ctrsm, FMA shapes)
        #pragma unroll
        for (int i = k + 1; i < NW; i++) {
            yr[i] = yr[i] - fmaf(Ar[i][k], yr[k], -(Ai[i][k] * yi[k]));
            yi[i] = yi[i] - fmaf(Ar[i][k], yi[k],  (Ai[i][k] * yr[k]));
        }
    }

    // ==== backward solve (upper non-unit ctrsm): pre-inverted diagonal
    //      (c+d*r, FMA denom), FMA-contracted multiply/axpy ====
    float xr[NW], xi[NW];
    #pragma unroll
    for (int k = NW - 1; k >= 0; k--) {
        float ur = Ar[k][k], ui = Ai[k][k];
        float ivr, ivi;
        if (fabsf(ur) >= fabsf(ui)) {
            float ratio = ui / ur;
            float s = fmaf(ui, ratio, ur);
            float den = 1.0f / s;
            ivr = den;
            ivi = -(ratio * den);
        } else {
            float ratio = ur / ui;
            float s = fmaf(ur, ratio, ui);
            float den = 1.0f / s;
            ivr = ratio * den;
            ivi = -den;
        }
        float xkr = fmaf(ivr, yr[k], -(ivi * yi[k]));
        float xki = fmaf(ivr, yi[k],  (ivi * yr[k]));
        xr[k] = xkr;
        xi[k] = xki;
        #pragma unroll
        for (int i = 0; i < k; i++) {
            yr[i] = yr[i] - fmaf(xkr, Ar[i][k], -(xki * Ai[i][k]));
            yi[i] = yi[i] - fmaf(xkr, Ai[i][k],  (xki * Ar[i][k]));
        }
    }

    // ==== windowed spec dot, plain fp32, ascending n ====
    const float2* sp = (const float2*)spec;
    size_t bbase = (size_t)b * TT;
    float o_r = 0.0f, o_i = 0.0f;
    #pragma unroll
    for (int n = 0; n < NW; n++) {
        int tt2 = t + n - 3;
        if (tt2 >= 0 && tt2 < TT) {
            float2 v = sp[(bbase + (size_t)tt2) * FQ + f];
            float p1 = v.x * xr[n];
            float p2 = v.y * xi[n];
            o_r = o_r + (p1 - p2);
            float p3 = v.x * xi[n];
            float p4 = v.y * xr[n];
            o_i = o_i + (p3 + p4);
        }
    }

    float2 o;
    o.x = o_r;
    o.y = o_i;
    ((float2*)out)[idx] = o;
}

extern "C" void kernel_launch(void* const* d_in, const int* in_sizes, int n_in,
                              void* d_out, int out_size, void* d_ws, size_t ws_size,
                              hipStream_t stream) {
    const float* spec = (const float*)d_in[0];
    const float* ifc  = (const float*)d_in[1];
    const float* iRxx = (const float*)d_in[2];
    float* out = (float*)d_out;

    int blocks = (TOTAL + 255) / 256;
    mfwf_kernel<<<blocks, 256, 0, stream>>>(spec, ifc, iRxx, out);
}

// Round 15
// 55.766 us; speedup vs baseline: 3.3493x; 1.0020x over previous
//
#include <hip/hip_runtime.h>
#include <math.h>

#define BB 4
#define TT 600
#define FQ 481
#define NW 5
#define TOTAL (BB * TT * FQ)

// libgcc __divsc3 specialized to (1 + 0i) / (c + di): pure float Smith,
// den = c*r + d (or c + d*r), DIRECT divisions for both components,
// branch predicate |c| < |d| (ties -> else). No FMA (libgcc is baseline).
__device__ __forceinline__ void divsc3_recip(float c, float d, float& zr, float& zi) {
    if (fabsf(c) < fabsf(d)) {
        float ratio = c / d;
        float m = c * ratio;
        float den = m + d;
        zr = ratio / den;
        zi = -1.0f / den;
    } else {
        float ratio = d / c;
        float m = d * ratio;
        float den = c + m;
        zr = 1.0f / den;
        zi = -ratio / den;
    }
}

// 8B-aligned vector loads (rows are 8B-aligned, not 16B): memcpy keeps the
// compiler honest about alignment while still emitting dwordx4/dwordx2.
__device__ __forceinline__ float4 ld4(const float* p) {
    float4 v; __builtin_memcpy(&v, p, 16); return v;
}
__device__ __forceinline__ float2 ld2(const float* p) {
    float2 v; __builtin_memcpy(&v, p, 8); return v;
}

__global__ __launch_bounds__(256) void mfwf_kernel(
    const float* __restrict__ spec,   // (B,1,T,FQ,2)
    const float* __restrict__ ifc,    // (B,T,FQ,10)
    const float* __restrict__ iRxx,   // (B,T,FQ,50)
    float* __restrict__ out)          // (B,1,T,FQ,2)
{
    #pragma clang fp contract(off)
    int idx = blockIdx.x * 256 + threadIdx.x;
    if (idx >= TOTAL) return;

    int f  = idx % FQ;
    int bt = idx / FQ;
    int t  = bt % TT;
    int b  = bt / TT;

    // ---- load iRxx LOWER TRIANGLE + DIAG only (upper is discarded by the
    //      Hermitianize step): 9 VMEM instead of 25, 120 B of 200 B ----
    const float* p = iRxx + (size_t)idx * 50;
    float Ar[NW][NW], Ai[NW][NW];
    {
        float2 e0  = ld2(p + 0);                    // (0,0)
        float4 r1  = ld4(p + 10);                   // (1,0) (1,1)
        float4 r2a = ld4(p + 20);                   // (2,0) (2,1)
        float2 r2b = ld2(p + 24);                   // (2,2)
        float4 r3a = ld4(p + 30);                   // (3,0) (3,1)
        float4 r3b = ld4(p + 34);                   // (3,2) (3,3)
        float4 r4a = ld4(p + 40);                   // (4,0) (4,1)
        float4 r4b = ld4(p + 44);                   // (4,2) (4,3)
        float2 r4c = ld2(p + 48);                   // (4,4)
        Ar[0][0] = e0.x;  Ai[0][0] = e0.y;
        Ar[1][0] = r1.x;  Ai[1][0] = r1.y;
        Ar[1][1] = r1.z;  Ai[1][1] = r1.w;
        Ar[2][0] = r2a.x; Ai[2][0] = r2a.y;
        Ar[2][1] = r2a.z; Ai[2][1] = r2a.w;
        Ar[2][2] = r2b.x; Ai[2][2] = r2b.y;
        Ar[3][0] = r3a.x; Ai[3][0] = r3a.y;
        Ar[3][1] = r3a.z; Ai[3][1] = r3a.w;
        Ar[3][2] = r3b.x; Ai[3][2] = r3b.y;
        Ar[3][3] = r3b.z; Ai[3][3] = r3b.w;
        Ar[4][0] = r4a.x; Ai[4][0] = r4a.y;
        Ar[4][1] = r4a.z; Ai[4][1] = r4a.w;
        Ar[4][2] = r4b.x; Ai[4][2] = r4b.y;
        Ar[4][3] = r4b.z; Ai[4][3] = r4b.w;
        Ar[4][4] = r4c.x; Ai[4][4] = r4c.y;
    }

    // ---- Hermitianize + diagonal load (fp32, two roundings for dload) ----
    float tr0 = (((Ar[0][0] + Ar[1][1]) + Ar[2][2]) + Ar[3][3]) + Ar[4][4];
    float dml = tr0 * 1e-7f;
    float dload = dml + 1e-8f;
    #pragma unroll
    for (int i = 0; i < NW; i++) {
        Ai[i][i] = 0.0f;
        #pragma unroll
        for (int j = i + 1; j < NW; j++) {
            Ar[i][j] = Ar[j][i];
            Ai[i][j] = -Ai[j][i];
        }
    }
    #pragma unroll
    for (int i = 0; i < NW; i++) {
        Ar[i][i] = Ar[i][i] + dload;
    }

    // ---- rhs: 3 VMEM (x4,x4,x2) ----
    const float* q = ifc + (size_t)idx * 10;
    float yr[NW], yi[NW];
    {
        float4 y01 = ld4(q + 0);
        float4 y23 = ld4(q + 4);
        float2 y4  = ld2(q + 8);
        yr[0] = y01.x; yi[0] = y01.y;
        yr[1] = y01.z; yi[1] = y01.w;
        yr[2] = y23.x; yi[2] = y23.y;
        yr[3] = y23.z; yi[3] = y23.w;
        yr[4] = y4.x;  yi[4] = y4.y;
    }

    // ==== netlib cgetf2 (gfortran) + OpenBLAS FMA-contracted kernels ====
    #pragma unroll
    for (int k = 0; k < NW; k++) {
        // icamax: first max of CABS1 = |re|+|im| (float), strict >
        int bi = k;
        float bm = fabsf(Ar[k][k]) + fabsf(Ai[k][k]);
        #pragma unroll
        for (int i = k + 1; i < NW; i++) {
            float m = fabsf(Ar[i][k]) + fabsf(Ai[i][k]);
            if (m > bm) { bm = m; bi = i; }
        }
        // swap rows k <-> bi on columns >= k only (bit-identical: cols < k
        // of rows >= k are dead after step k) + rhs
        #pragma unroll
        for (int i = k + 1; i < NW; i++) {
            bool sw = (bi == i);
            #pragma unroll
            for (int j = k; j < NW; j++) {
                float a = Ar[k][j], c = Ar[i][j];
                Ar[k][j] = sw ? c : a;  Ar[i][j] = sw ? a : c;
                a = Ai[k][j]; c = Ai[i][j];
                Ai[k][j] = sw ? c : a;  Ai[i][j] = sw ? a : c;
            }
            float a = yr[k], c = yr[i];
            yr[k] = sw ? c : a;  yr[i] = sw ? a : c;
            a = yi[k]; c = yi[i];
            yi[k] = sw ? c : a;  yi[i] = sw ? a : c;
        }
        // CONE / A(k,k) via exact __divsc3 (direct divisions)
        float ivr, ivi;
        divsc3_recip(Ar[k][k], Ai[k][k], ivr, ivi);
        // CSCAL tail (arch-compiled, FMA-contracted)
        #pragma unroll
        for (int i = k + 1; i < NW; i++) {
            float xr_ = Ar[i][k], xi_ = Ai[i][k];
            float Lr = fmaf(ivr, xr_, -(ivi * xi_));
            float Li = fmaf(ivr, xi_,  (ivi * xr_));
            Ar[i][k] = Lr;
            Ai[i][k] = Li;
        }
        // CGERU (FMA-contracted), alpha = -1: temp = -U[k][j] exact
        #pragma unroll
        for (int j = k + 1; j < NW; j++) {
            float tr_ = -Ar[k][j], ti_ = -Ai[k][j];
            #pragma unroll
            for (int i = k + 1; i < NW; i++) {
                Ar[i][j] = Ar[i][j] + fmaf(tr_, Ar[i][k], -(ti_ * Ai[i][k]));
                Ai[i][j] = Ai[i][j] + fmaf(tr_, Ai[i][k],  (ti_ * Ar[i][k]));
            }
        }
        // forward solve on rhs (laswp + unit-L ctrsm, FMA shapes)
        #pragma unroll
        for (int i = k + 1; i < NW; i++) {
            yr[i] = yr[i] - fmaf(Ar[i][k], yr[k], -(Ai[i][k] * yi[k]));
            yi[i] = yi[i] - fmaf(Ar[i][k], yi[k],  (Ai[i][k] * yr[k]));
        }
    }

    // ==== backward solve (upper non-unit ctrsm): pre-inverted diagonal
    //      (c+d*r, FMA denom), FMA-contracted multiply/axpy ====
    float xr[NW], xi[NW];
    #pragma unroll
    for (int k = NW - 1; k >= 0; k--) {
        float ur = Ar[k][k], ui = Ai[k][k];
        float ivr, ivi;
        if (fabsf(ur) >= fabsf(ui)) {
            float ratio = ui / ur;
            float s = fmaf(ui, ratio, ur);
            float den = 1.0f / s;
            ivr = den;
            ivi = -(ratio * den);
        } else {
            float ratio = ur / ui;
            float s = fmaf(ur, ratio, ui);
            float den = 1.0f / s;
            ivr = ratio * den;
            ivi = -den;
        }
        float xkr = fmaf(ivr, yr[k], -(ivi * yi[k]));
        float xki = fmaf(ivr, yi[k],  (ivi * yr[k]));
        xr[k] = xkr;
        xi[k] = xki;
        #pragma unroll
        for (int i = 0; i < k; i++) {
            yr[i] = yr[i] - fmaf(xkr, Ar[i][k], -(xki * Ai[i][k]));
            yi[i] = yi[i] - fmaf(xkr, Ai[i][k],  (xki * Ar[i][k]));
        }
    }

    // ==== windowed spec dot, plain fp32, ascending n ====
    const float2* sp = (const float2*)spec;
    size_t bbase = (size_t)b * TT;
    float o_r = 0.0f, o_i = 0.0f;
    #pragma unroll
    for (int n = 0; n < NW; n++) {
        int tt2 = t + n - 3;
        if (tt2 >= 0 && tt2 < TT) {
            float2 v = sp[(bbase + (size_t)tt2) * FQ + f];
            float p1 = v.x * xr[n];
            float p2 = v.y * xi[n];
            o_r = o_r + (p1 - p2);
            float p3 = v.x * xi[n];
            float p4 = v.y * xr[n];
            o_i = o_i + (p3 + p4);
        }
    }

    float2 o;
    o.x = o_r;
    o.y = o_i;
    ((float2*)out)[idx] = o;
}

extern "C" void kernel_launch(void* const* d_in, const int* in_sizes, int n_in,
                              void* d_out, int out_size, void* d_ws, size_t ws_size,
                              hipStream_t stream) {
    const float* spec = (const float*)d_in[0];
    const float* ifc  = (const float*)d_in[1];
    const float* iRxx = (const float*)d_in[2];
    float* out = (float*)d_out;

    int blocks = (TOTAL + 255) / 256;
    mfwf_kernel<<<blocks, 256, 0, stream>>>(spec, ifc, iRxx, out);
}